// Round 17
// baseline (284.279 us; speedup 1.0000x reference)
//
#include <hip/hip_runtime.h>
#include <hip/hip_bf16.h>

typedef __attribute__((ext_vector_type(16))) float  f32x16;
typedef __attribute__((ext_vector_type(8)))  __bf16 bf16x8;
typedef __attribute__((ext_vector_type(8)))  short  short8;

#define KDIM 4096
#define NDIM 4096
#define BK   64
#define NT   (KDIM / BK)     // 64 K-tiles

__device__ inline unsigned short f2bf(float f) {
    union { float f; unsigned u; } v; v.f = f;
    unsigned r = v.u + 0x7fffu + ((v.u >> 16) & 1u);   // RNE
    return (unsigned short)(r >> 16);
}

// ---------- kernel 1: fused prep (dequant W + cvt x), block-uniform split ----
__global__ void prep(const int* __restrict__ wq, const float* __restrict__ absmax,
                     const float* __restrict__ code, short* __restrict__ wout,
                     const float* __restrict__ xin, short* __restrict__ xout,
                     int nwblocks) {
    __shared__ float cs[256];
    cs[threadIdx.x] = code[threadIdx.x];
    __syncthreads();
    if (blockIdx.x < (unsigned)nwblocks) {
        size_t idx = ((size_t)blockIdx.x * blockDim.x + threadIdx.x) * 8;
        float am = absmax[idx >> 12];                  // BLOCKSIZE = 4096
        int4 q0 = *(const int4*)(wq + idx);
        int4 q1 = *(const int4*)(wq + idx + 4);
        short8 r;
        r[0] = (short)f2bf(cs[q0.x] * am);
        r[1] = (short)f2bf(cs[q0.y] * am);
        r[2] = (short)f2bf(cs[q0.z] * am);
        r[3] = (short)f2bf(cs[q0.w] * am);
        r[4] = (short)f2bf(cs[q1.x] * am);
        r[5] = (short)f2bf(cs[q1.y] * am);
        r[6] = (short)f2bf(cs[q1.z] * am);
        r[7] = (short)f2bf(cs[q1.w] * am);
        *(short8*)(wout + idx) = r;
    } else {
        size_t idx = ((size_t)(blockIdx.x - nwblocks) * blockDim.x + threadIdx.x) * 8;
        float4 a = *(const float4*)(xin + idx);
        float4 b = *(const float4*)(xin + idx + 4);
        short8 r;
        r[0] = (short)f2bf(a.x); r[1] = (short)f2bf(a.y);
        r[2] = (short)f2bf(a.z); r[3] = (short)f2bf(a.w);
        r[4] = (short)f2bf(b.x); r[5] = (short)f2bf(b.y);
        r[6] = (short)f2bf(b.z); r[7] = (short)f2bf(b.w);
        *(short8*)(xout + idx) = r;
    }
}

// ---------- kernel 2: 256x256 2-phase NT GEMM, 32x32x16 MFMA ----------------
// R12/R16 schedule EXACTLY (staging, vmcnt(4) accounting, barriers, slot
// lifetimes all unchanged); only the MFMA shape + matched swizzle change.
// PhA(t): {8 B + 8 A-lo(QR0) ds_read | stage B-lo(t+1),A-hi(t+1)}
//         -> 16 MFMA_32x32(QR0) -> bar
// PhB(t): {8 A-hi(QR1) ds_read | stage A-lo(t+2),B-hi(t+2)}
//         -> 16 MFMA_32x32(QR1) -> vmcnt(4) -> bar
// Swizzle (R5 conflict bug FIXED): rows 8 apart bank-alias (1024B), so the
// slot XOR must include (rl>>3):  swz = (rl&7) ^ ((rl>>3)&3).
// Write-side involution S'(d) = (((d>>7)&7) ^ ((d>>10)&3))<<4 (reads bits
// 7-11, XORs 4-6).  Bank audit: 8 lanes per 16B slot = b128 minimum.
// Fragment/epilogue math for 32x32x16 verified correct in R4/R5 (absmax 2.0).
__global__ __launch_bounds__(512, 2) void gemm256(
    const short* __restrict__ A, const short* __restrict__ Bm,
    const float* __restrict__ bias, float* __restrict__ C, int M) {

    __shared__ __attribute__((aligned(128))) char lds[131072];

    const int tid  = threadIdx.x;
    const int wid  = tid >> 6;
    const int lane = tid & 63;
    const int wr   = wid >> 2;        // 0..1 : 64-row piece within quadrant
    const int wc   = wid & 3;         // 0..3 : 32-col piece within quadrant
    const int rl   = lane & 31;       // A row / B col within 32
    const int hi   = lane >> 5;       // k half of fragment

    // XCD-aware chunked swizzle (512 wg, %8==0 -> bijective)
    const int nwg  = gridDim.x;
    const int cpx  = nwg >> 3;
    const int swzb = (blockIdx.x & 7) * cpx + (blockIdx.x >> 3);
    const int bx   = swzb & 15;              // NDIM/256 = 16 tiles, fastest
    const int by   = swzb >> 4;
    const int tileM = by * 256, tileN = bx * 256;

    // ---- read-side swizzle: slot = (2ks+hi) ^ (rl&7) ^ ((rl>>3)&3)
    const int swz = (rl & 7) ^ ((rl >> 3) & 3);
    int kb[4];
    #pragma unroll
    for (int ks = 0; ks < 4; ++ks) kb[ks] = ((2 * ks + hi) ^ swz) << 4;
    const int arow = (wr * 64 + rl) * 128;   // + QR*16384 + ml*4096
    const int brow = (wc * 32 + rl) * 128;   // + ni*16384

    // ---- staging: linear LDS dest (tid*16), source pre-XORed with S'
    const int sx = (((tid >> 3) & 7) ^ ((tid >> 6) & 3)) << 4;
    const int u0 = (tid * 16) ^ sx;
    const int u1 = (8192 + tid * 16) ^ sx;
    const int srow0 = u0 >> 7, scol0 = (u0 & 127) >> 1;   // rows 0..63
    const int srow1 = u1 >> 7, scol1 = (u1 & 127) >> 1;   // rows 64..127

    const short* pA0 = A  + (size_t)(tileM + srow0) * KDIM + scol0;
    const short* pA1 = A  + (size_t)(tileM + srow1) * KDIM + scol1;
    const short* pB0 = Bm + (size_t)(tileN + srow0) * KDIM + scol0;
    const short* pB1 = Bm + (size_t)(tileN + srow1) * KDIM + scol1;

#define LDSA(b) (lds + (b) * 65536)
#define LDSB(b) (lds + (b) * 65536 + 32768)

#define STAGE(PM0, PM1, REG, H, KS) do {                                       \
    char* _l = (REG) + (H) * 16384 + wid * 1024;                               \
    __builtin_amdgcn_global_load_lds(                                          \
        (const __attribute__((address_space(1))) void*)((PM0) + (size_t)(H) * 128 * KDIM + (KS)), \
        (__attribute__((address_space(3))) void*)(_l), 16, 0, 0);              \
    __builtin_amdgcn_global_load_lds(                                          \
        (const __attribute__((address_space(1))) void*)((PM1) + (size_t)(H) * 128 * KDIM + (KS)), \
        (__attribute__((address_space(3))) void*)(_l + 8192), 16, 0, 0);       \
} while (0)

    f32x16 acc[4][2] = {};     // [mi = qr*2+ml][ni = qc]
    bf16x8 aF[2][4];           // [ml][ks]  (current QR; dead after MFMA)
    bf16x8 bF[2][4];           // [ni][ks]  (persist across both phases)

#define RDA32(b, QR) do {                                                      \
    _Pragma("unroll") for (int ml = 0; ml < 2; ++ml) {                         \
        const char* _p = LDSA(b) + (QR) * 16384 + ml * 4096 + arow;            \
        _Pragma("unroll") for (int ks = 0; ks < 4; ++ks)                       \
            aF[ml][ks] = *(const bf16x8*)(_p + kb[ks]);                        \
    } } while (0)

#define RDB32(b) do {                                                          \
    _Pragma("unroll") for (int ni = 0; ni < 2; ++ni) {                         \
        const char* _p = LDSB(b) + ni * 16384 + brow;                          \
        _Pragma("unroll") for (int ks = 0; ks < 4; ++ks)                       \
            bF[ni][ks] = *(const bf16x8*)(_p + kb[ks]);                        \
    } } while (0)

#define MFMA16W(QR) do {                                                       \
    __builtin_amdgcn_s_setprio(1);                                             \
    _Pragma("unroll") for (int ks = 0; ks < 4; ++ks)                           \
    _Pragma("unroll") for (int ml = 0; ml < 2; ++ml)                           \
    _Pragma("unroll") for (int ni = 0; ni < 2; ++ni)                           \
        acc[(QR) * 2 + ml][ni] = __builtin_amdgcn_mfma_f32_32x32x16_bf16(      \
            aF[ml][ks], bF[ni][ks], acc[(QR) * 2 + ml][ni], 0, 0, 0);          \
    __builtin_amdgcn_s_setprio(0);                                             \
} while (0)

#define BAR() __builtin_amdgcn_s_barrier()

    // PhA(t), buf b: B-reads first, then A(QR0); stages B-lo(t+1),A-hi(t+1)
#define PHA(b, KS, DO_ST) do {                                                 \
    RDB32(b); RDA32(b, 0);                                                     \
    if (DO_ST) {                                                               \
        STAGE(pB0, pB1, LDSB(1 - (b)), 0, KS);                                 \
        STAGE(pA0, pA1, LDSA(1 - (b)), 1, KS);                                 \
    }                                                                          \
    MFMA16W(0); BAR();                                                         \
} while (0)

    // PhB(t), buf b: reads A(QR1); stages A-lo(t+2),B-hi(t+2) -> buf b
#define PHB(b, KS, DO_ST, VMN) do {                                            \
    RDA32(b, 1);                                                               \
    if (DO_ST) {                                                               \
        STAGE(pA0, pA1, LDSA(b), 0, KS);                                       \
        STAGE(pB0, pB1, LDSB(b), 1, KS);                                       \
    }                                                                          \
    MFMA16W(1);                                                                \
    if ((VMN) == 4)      asm volatile("s_waitcnt vmcnt(4)" ::: "memory");      \
    else if ((VMN) == 0) asm volatile("s_waitcnt vmcnt(0)" ::: "memory");      \
    BAR();                                                                     \
} while (0)

    // ---- prologue: tile0 all 4 halves + tile1 {A-lo, B-hi}  (= PhB(-1))
    STAGE(pA0, pA1, LDSA(0), 0, 0);
    STAGE(pA0, pA1, LDSA(0), 1, 0);
    STAGE(pB0, pB1, LDSB(0), 0, 0);
    STAGE(pB0, pB1, LDSB(0), 1, 0);
    STAGE(pA0, pA1, LDSA(1), 0, BK);
    STAGE(pB0, pB1, LDSB(1), 1, BK);
    asm volatile("s_waitcnt vmcnt(4)" ::: "memory");   // tile0 landed
    BAR();

    // ---- main loop: tiles 0..61 (31 iterations x 2 tiles)
    for (int it = 0; it < NT / 2 - 1; ++it) {
        const int k1 = ((2 * it + 1) * BK) & (KDIM - 1);
        const int k2 = ((2 * it + 2) * BK) & (KDIM - 1);
        const int k3 = ((2 * it + 3) * BK) & (KDIM - 1);
        PHA(0, k1, 1);          // t=2it:   stage B-lo/A-hi(t+1)
        PHB(0, k2, 1, 4);       //          stage A-lo/B-hi(t+2)
        PHA(1, k2, 1);          // t=2it+1: stage B-lo/A-hi(t+2)
        PHB(1, k3, 1, 4);       //          stage A-lo/B-hi(t+3)
    }
    // ---- tail: tiles 62, 63
    {
        const int k1 = ((NT - 1) * BK) & (KDIM - 1);   // tile 63 offset
        PHA(0, k1, 1);          // t=62: stage B-lo/A-hi(63)
        PHB(0, 0, 0, 0);        //       drain all staging
        PHA(1, 0, 0);           // t=63
        PHB(1, 0, 0, -1);
    }

    // ---- epilogue: 32x32 C/D layout col = lane&31, row = (reg&3)+8*(reg>>2)+4*hi
    float bv[2];
    #pragma unroll
    for (int ni = 0; ni < 2; ++ni)
        bv[ni] = bias[tileN + ni * 128 + wc * 32 + rl];

    #pragma unroll
    for (int mi = 0; mi < 4; ++mi)
    #pragma unroll
    for (int ni = 0; ni < 2; ++ni) {
        f32x16 v = acc[mi][ni];
        const int col   = tileN + ni * 128 + wc * 32 + rl;
        const int rbase = tileM + (mi >> 1) * 128 + wr * 64 + (mi & 1) * 32 + 4 * hi;
        #pragma unroll
        for (int reg = 0; reg < 16; ++reg) {
            const int row = rbase + (reg & 3) + 8 * (reg >> 2);
            C[(size_t)row * NDIM + col] = v[reg] + bv[ni];
        }
    }
}

extern "C" void kernel_launch(void* const* d_in, const int* in_sizes, int n_in,
                              void* d_out, int out_size, void* d_ws, size_t ws_size,
                              hipStream_t stream) {
    const float* x      = (const float*)d_in[0];
    const int*   wq     = (const int*)  d_in[1];
    const float* absmax = (const float*)d_in[2];
    const float* code   = (const float*)d_in[3];
    const float* bias   = (const float*)d_in[4];
    float* out = (float*)d_out;

    const int K = KDIM, N = NDIM;
    const int M = in_sizes[0] / K;            // 8192

    short* wbf = (short*)d_ws;                // [N][K] bf16: 32 MiB
    short* xbf = wbf + (size_t)N * K;         // [M][K] bf16: 64 MiB

    const int nwblocks = (N * K / 8) / 256;            // 8192 (exact)
    const int nxblocks = (int)((size_t)M * K / 8 / 256);
    prep<<<nwblocks + nxblocks, 256, 0, stream>>>(wq, absmax, code, wbf, x, xbf, nwblocks);

    const int nwg = (M / 256) * (N / 256);    // 512, %8 == 0
    gemm256<<<nwg, 512, 0, stream>>>(xbf, wbf, bias, out, M);
}

// Round 18
// 265.896 us; speedup vs baseline: 1.0691x; 1.0691x over previous
//
#include <hip/hip_runtime.h>
#include <hip/hip_bf16.h>

typedef __attribute__((ext_vector_type(4))) float  f32x4;
typedef __attribute__((ext_vector_type(8))) __bf16 bf16x8;
typedef __attribute__((ext_vector_type(8))) short  short8;

#define KDIM 4096
#define NDIM 4096
#define BK   64
#define NT   (KDIM / BK)     // 64 K-tiles

__device__ inline unsigned short f2bf(float f) {
    union { float f; unsigned u; } v; v.f = f;
    unsigned r = v.u + 0x7fffu + ((v.u >> 16) & 1u);   // RNE
    return (unsigned short)(r >> 16);
}

// ---------- kernel 1: fused prep (dequant W + cvt x), block-uniform split ----
__global__ void prep(const int* __restrict__ wq, const float* __restrict__ absmax,
                     const float* __restrict__ code, short* __restrict__ wout,
                     const float* __restrict__ xin, short* __restrict__ xout,
                     int nwblocks) {
    __shared__ float cs[256];
    cs[threadIdx.x] = code[threadIdx.x];
    __syncthreads();
    if (blockIdx.x < (unsigned)nwblocks) {
        size_t idx = ((size_t)blockIdx.x * blockDim.x + threadIdx.x) * 8;
        float am = absmax[idx >> 12];                  // BLOCKSIZE = 4096
        int4 q0 = *(const int4*)(wq + idx);
        int4 q1 = *(const int4*)(wq + idx + 4);
        short8 r;
        r[0] = (short)f2bf(cs[q0.x] * am);
        r[1] = (short)f2bf(cs[q0.y] * am);
        r[2] = (short)f2bf(cs[q0.z] * am);
        r[3] = (short)f2bf(cs[q0.w] * am);
        r[4] = (short)f2bf(cs[q1.x] * am);
        r[5] = (short)f2bf(cs[q1.y] * am);
        r[6] = (short)f2bf(cs[q1.z] * am);
        r[7] = (short)f2bf(cs[q1.w] * am);
        *(short8*)(wout + idx) = r;
    } else {
        size_t idx = ((size_t)(blockIdx.x - nwblocks) * blockDim.x + threadIdx.x) * 8;
        float4 a = *(const float4*)(xin + idx);
        float4 b = *(const float4*)(xin + idx + 4);
        short8 r;
        r[0] = (short)f2bf(a.x); r[1] = (short)f2bf(a.y);
        r[2] = (short)f2bf(a.z); r[3] = (short)f2bf(a.w);
        r[4] = (short)f2bf(b.x); r[5] = (short)f2bf(b.y);
        r[6] = (short)f2bf(b.z); r[7] = (short)f2bf(b.w);
        *(short8*)(xout + idx) = r;
    }
}

// ---------- kernel 2: 256x256 2-phase bf16 NT GEMM (verified best) ----------
// C = A[M,K] * B[N,K]^T + bias.  Compiler-counted lgkm waits (no manual
// fences mid-phase): first MFMAs overlap the tail of the ds_read burst.
// PhA(t): {8 B ds_read, 8 A-lo ds_read | stage B-lo(t+1),A-hi(t+1)}
//         -> 32 MFMA(QR0) -> bar
// PhB(t): {8 A-hi ds_read | stage A-lo(t+2),B-hi(t+2)}
//         -> 32 MFMA(QR1) -> vmcnt(4) -> bar
// All ds_reads occur AFTER the barrier that follows every wave's counted
// drain (vmcnt is per-wave; cross-wave staging visibility needs the barrier).
// Swizzle S(a)=((a>>7)&7)<<4: linear global_load_lds dest + pre-swizzled
// source; ds_read at a^S(a).  Measured: 0 bank conflicts.
__global__ __launch_bounds__(512, 2) void gemm256(
    const short* __restrict__ A, const short* __restrict__ Bm,
    const float* __restrict__ bias, float* __restrict__ C, int M) {

    __shared__ __attribute__((aligned(128))) char lds[131072];

    const int tid  = threadIdx.x;
    const int wid  = tid >> 6;
    const int lane = tid & 63;
    const int wr   = wid >> 2;        // 0..1 : 64-row piece within quadrant
    const int wc   = wid & 3;         // 0..3 : 32-col piece within quadrant
    const int lr   = lane & 15;
    const int kl   = (lane >> 4) * 8; // k element offset of fragment

    // XCD-aware chunked swizzle (512 wg, %8==0 -> bijective)
    const int nwg  = gridDim.x;
    const int cpx  = nwg >> 3;
    const int swzb = (blockIdx.x & 7) * cpx + (blockIdx.x >> 3);
    const int bx   = swzb & 15;              // NDIM/256 = 16 tiles, fastest
    const int by   = swzb >> 4;
    const int tileM = by * 256, tileN = bx * 256;

    // ---- read-side swizzle: row&7 == lr&7 for both A and B fragments
    const int swb = (lr & 7) << 4;
    const int kb0 = (kl * 2) ^ swb;
    const int kb1 = (kl * 2 + 64) ^ swb;
    const int arow = (wr * 64 + lr) * 128;   // region-relative byte row base
    const int brow = (wc * 32 + lr) * 128;

    // ---- staging: linear LDS dest (tid*16), source pre-XORed with S
    const int u0 = (tid * 16) ^ (((tid >> 3) & 7) << 4);
    const int u1 = (8192 + tid * 16) ^ (((tid >> 3) & 7) << 4);
    const int srow0 = u0 >> 7, scol0 = (u0 & 127) >> 1;   // rows 0..63
    const int srow1 = u1 >> 7, scol1 = (u1 & 127) >> 1;   // rows 64..127

    const short* pA0 = A  + (size_t)(tileM + srow0) * KDIM + scol0;
    const short* pA1 = A  + (size_t)(tileM + srow1) * KDIM + scol1;
    const short* pB0 = Bm + (size_t)(tileN + srow0) * KDIM + scol0;
    const short* pB1 = Bm + (size_t)(tileN + srow1) * KDIM + scol1;

#define LDSA(b) (lds + (b) * 65536)
#define LDSB(b) (lds + (b) * 65536 + 32768)

#define STAGE(PM0, PM1, REG, H, KS) do {                                       \
    char* _l = (REG) + (H) * 16384 + wid * 1024;                               \
    __builtin_amdgcn_global_load_lds(                                          \
        (const __attribute__((address_space(1))) void*)((PM0) + (size_t)(H) * 128 * KDIM + (KS)), \
        (__attribute__((address_space(3))) void*)(_l), 16, 0, 0);              \
    __builtin_amdgcn_global_load_lds(                                          \
        (const __attribute__((address_space(1))) void*)((PM1) + (size_t)(H) * 128 * KDIM + (KS)), \
        (__attribute__((address_space(3))) void*)(_l + 8192), 16, 0, 0);       \
} while (0)

    f32x4  acc[2][2][4][2] = {};   // [qr][qc][mi][ni]
    bf16x8 aF[4][2];               // [mi][ks]  (current QR)
    bf16x8 bF0[2][2], bF1[2][2];   // [ni][ks]  (QC=0 and QC=1, both kept live)

#define RDA(b, QR) do {                                                        \
    _Pragma("unroll") for (int mi = 0; mi < 4; ++mi) {                         \
        const char* _p = LDSA(b) + (QR) * 16384 + mi * 2048 + arow;            \
        aF[mi][0] = *(const bf16x8*)(_p + kb0);                                \
        aF[mi][1] = *(const bf16x8*)(_p + kb1);                                \
    } } while (0)

#define RDB(b, QC, DST) do {                                                   \
    _Pragma("unroll") for (int ni = 0; ni < 2; ++ni) {                         \
        const char* _p = LDSB(b) + (QC) * 16384 + ni * 2048 + brow;            \
        DST[ni][0] = *(const bf16x8*)(_p + kb0);                               \
        DST[ni][1] = *(const bf16x8*)(_p + kb1);                               \
    } } while (0)

#define MFMA32(QR) do {                                                        \
    __builtin_amdgcn_s_setprio(1);                                             \
    _Pragma("unroll") for (int ks = 0; ks < 2; ++ks)                           \
    _Pragma("unroll") for (int mi = 0; mi < 4; ++mi) {                         \
        _Pragma("unroll") for (int ni = 0; ni < 2; ++ni)                       \
            acc[QR][0][mi][ni] = __builtin_amdgcn_mfma_f32_16x16x32_bf16(      \
                aF[mi][ks], bF0[ni][ks], acc[QR][0][mi][ni], 0, 0, 0);         \
        _Pragma("unroll") for (int ni = 0; ni < 2; ++ni)                       \
            acc[QR][1][mi][ni] = __builtin_amdgcn_mfma_f32_16x16x32_bf16(      \
                aF[mi][ks], bF1[ni][ks], acc[QR][1][mi][ni], 0, 0, 0);         \
    }                                                                          \
    __builtin_amdgcn_s_setprio(0);                                             \
} while (0)

#define BAR() __builtin_amdgcn_s_barrier()

    // PhA(t), buf b: B-reads first, then A-lo; stages B-lo(t+1),A-hi(t+1)
#define PHA(b, KS, DO_ST) do {                                                 \
    RDB(b, 0, bF0); RDB(b, 1, bF1); RDA(b, 0);                                 \
    if (DO_ST) {                                                               \
        STAGE(pB0, pB1, LDSB(1 - (b)), 0, KS);                                 \
        STAGE(pA0, pA1, LDSA(1 - (b)), 1, KS);                                 \
    }                                                                          \
    MFMA32(0); BAR();                                                          \
} while (0)

    // PhB(t), buf b: reads A-hi; stages A-lo(t+2),B-hi(t+2) -> buf b
#define PHB(b, KS, DO_ST, VMN) do {                                            \
    RDA(b, 1);                                                                 \
    if (DO_ST) {                                                               \
        STAGE(pA0, pA1, LDSA(b), 0, KS);                                       \
        STAGE(pB0, pB1, LDSB(b), 1, KS);                                       \
    }                                                                          \
    MFMA32(1);                                                                 \
    if ((VMN) == 4)      asm volatile("s_waitcnt vmcnt(4)" ::: "memory");      \
    else if ((VMN) == 0) asm volatile("s_waitcnt vmcnt(0)" ::: "memory");      \
    BAR();                                                                     \
} while (0)

    // ---- prologue: tile0 all 4 halves + tile1 {A-lo, B-hi}  (= PhB(-1))
    STAGE(pA0, pA1, LDSA(0), 0, 0);
    STAGE(pA0, pA1, LDSA(0), 1, 0);
    STAGE(pB0, pB1, LDSB(0), 0, 0);
    STAGE(pB0, pB1, LDSB(0), 1, 0);
    STAGE(pA0, pA1, LDSA(1), 0, BK);
    STAGE(pB0, pB1, LDSB(1), 1, BK);
    asm volatile("s_waitcnt vmcnt(4)" ::: "memory");   // tile0 landed
    BAR();

    // ---- main loop: tiles 0..61 (31 iterations x 2 tiles)
    for (int it = 0; it < NT / 2 - 1; ++it) {
        const int k1 = ((2 * it + 1) * BK) & (KDIM - 1);
        const int k2 = ((2 * it + 2) * BK) & (KDIM - 1);
        const int k3 = ((2 * it + 3) * BK) & (KDIM - 1);
        PHA(0, k1, 1);          // t=2it:   stage B-lo/A-hi(t+1)
        PHB(0, k2, 1, 4);       //          stage A-lo/B-hi(t+2)
        PHA(1, k2, 1);          // t=2it+1: stage B-lo/A-hi(t+2)
        PHB(1, k3, 1, 4);       //          stage A-lo/B-hi(t+3)
    }
    // ---- tail: tiles 62, 63
    {
        const int k1 = ((NT - 1) * BK) & (KDIM - 1);   // tile 63 offset
        PHA(0, k1, 1);          // t=62: stage B-lo/A-hi(63)
        PHB(0, 0, 0, 0);        //       drain all staging
        PHA(1, 0, 0);           // t=63
        PHB(1, 0, 0, -1);
    }

    // ---- epilogue: C/D layout col = lane&15, row = (lane>>4)*4 + reg
    const int r4 = (lane >> 4) * 4;
    float bv[2][2];
    #pragma unroll
    for (int qc = 0; qc < 2; ++qc)
        #pragma unroll
        for (int ni = 0; ni < 2; ++ni)
            bv[qc][ni] = bias[tileN + qc * 128 + wc * 32 + ni * 16 + lr];

    #pragma unroll
    for (int qr = 0; qr < 2; ++qr)
    #pragma unroll
    for (int qc = 0; qc < 2; ++qc)
    #pragma unroll
    for (int mi = 0; mi < 4; ++mi)
    #pragma unroll
    for (int ni = 0; ni < 2; ++ni) {
        const int row0 = tileM + qr * 128 + wr * 64 + mi * 16 + r4;
        const int col  = tileN + qc * 128 + wc * 32 + ni * 16 + lr;
        f32x4 v = acc[qr][qc][mi][ni];
        #pragma unroll
        for (int j = 0; j < 4; ++j)
            C[(size_t)(row0 + j) * NDIM + col] = v[j] + bv[qc][ni];
    }
}

extern "C" void kernel_launch(void* const* d_in, const int* in_sizes, int n_in,
                              void* d_out, int out_size, void* d_ws, size_t ws_size,
                              hipStream_t stream) {
    const float* x      = (const float*)d_in[0];
    const int*   wq     = (const int*)  d_in[1];
    const float* absmax = (const float*)d_in[2];
    const float* code   = (const float*)d_in[3];
    const float* bias   = (const float*)d_in[4];
    float* out = (float*)d_out;

    const int K = KDIM, N = NDIM;
    const int M = in_sizes[0] / K;            // 8192

    short* wbf = (short*)d_ws;                // [N][K] bf16: 32 MiB
    short* xbf = wbf + (size_t)N * K;         // [M][K] bf16: 64 MiB

    const int nwblocks = (N * K / 8) / 256;            // 8192 (exact)
    const int nxblocks = (int)((size_t)M * K / 8 / 256);
    prep<<<nwblocks + nxblocks, 256, 0, stream>>>(wq, absmax, code, wbf, x, xbf, nwblocks);

    const int nwg = (M / 256) * (N / 256);    // 512, %8 == 0
    gemm256<<<nwg, 512, 0, stream>>>(xbf, wbf, bias, out, M);
}